// Round 5
// baseline (239.110 us; speedup 1.0000x reference)
//
#include <hip/hip_runtime.h>
#include <cstdint>
#include <cstddef>

// Shapes fixed by the reference harness.
#define MM 2048
#define KK 4096
#define NN 4096
#define GG 32   // K / 128 groups
#define BM 128
#define BN 256
#define BK 64
#define NTILES (KK / BK)   // 64 k-tiles

typedef _Float16 half8_t __attribute__((ext_vector_type(8)));
typedef _Float16 half4_t __attribute__((ext_vector_type(4)));
typedef _Float16 half2_t __attribute__((ext_vector_type(2)));
typedef float f32x4 __attribute__((ext_vector_type(4)));

__device__ __forceinline__ void load_lds16(const void* gptr, void* lptr) {
  // 16B-per-lane direct global->LDS (emits global_load_lds_dwordx4).
  // LDS dest = wave-uniform base + lane*16 (implicit); the GLOBAL source is
  // exactly the per-lane pointer passed (no implicit lane term).
  __builtin_amdgcn_global_load_lds(
      (const __attribute__((address_space(1))) unsigned int*)gptr,
      (__attribute__((address_space(3))) unsigned int*)lptr, 16, 0, 0);
}

__device__ __forceinline__ half2_t h2_from_u32(unsigned v) {
  union { unsigned u; half2_t h; } x; x.u = v; return x.h;
}

// Magic-number nibble dequant: f16 bits (0x6400|q) represent 1024+q exactly
// for q in [0,16). w = ((1024+q) - 1024)*s + (-z*s): the 1024 is subtracted
// exactly in f16 before the scale is applied (no cancellation error).
__device__ __forceinline__ half8_t dq8(unsigned d0, unsigned d1,
                                       half2_t s2, half2_t c2) {
  const unsigned M = 0x64006400u;
  const half2_t off = (half2_t){(_Float16)1024.0f, (_Float16)1024.0f};
  unsigned u0 = M | ((d0 & 0xFFu)         | ((d0 & 0xFF00u) << 8));
  unsigned u1 = M | (((d0 >> 16) & 0xFFu) | ((d0 >> 24) << 16));
  unsigned u2 = M | ((d1 & 0xFFu)         | ((d1 & 0xFF00u) << 8));
  unsigned u3 = M | (((d1 >> 16) & 0xFFu) | ((d1 >> 24) << 16));
  half2_t w0 = (h2_from_u32(u0) - off) * s2 + c2;
  half2_t w1 = (h2_from_u32(u1) - off) * s2 + c2;
  half2_t w2 = (h2_from_u32(u2) - off) * s2 + c2;
  half2_t w3 = (h2_from_u32(u3) - off) * s2 + c2;
  half8_t r;
  r[0] = w0[0]; r[1] = w0[1]; r[2] = w1[0]; r[3] = w1[1];
  r[4] = w2[0]; r[5] = w2[1]; r[6] = w3[0]; r[7] = w3[1];
  return r;
}

// Merged prep, three block-uniform branches (all boundaries divisible by 256):
//  [0, ACNT8)            : A fp32 -> fp16, 8 elems/thread
//  [ACNT8, +WCNT8)       : qweight int32 -> raw uint8 pack, 8 elems/thread
//  [.., +SZCNT)          : (s, -z*s) f16x2 table, layout [g][n] (g-major so the
//                          GEMM can stage one g-row per global_load_lds)
#define ACNT8 (MM * KK / 8)   // 1048576
#define WCNT8 (NN * KK / 8)   // 2097152
#define SZCNT (NN * GG)       // 131072
__global__ void prep_kernel(const float* __restrict__ A, const int* __restrict__ q,
                            const float* __restrict__ scales, const float* __restrict__ zeros,
                            _Float16* __restrict__ Ah, unsigned char* __restrict__ Wq,
                            unsigned* __restrict__ SZT) {
  const int i = blockIdx.x * blockDim.x + threadIdx.x;
  if (i < ACNT8) {
    const float4 v0 = ((const float4*)A)[2 * (size_t)i];
    const float4 v1 = ((const float4*)A)[2 * (size_t)i + 1];
    half8_t h;
    h[0] = (_Float16)v0.x; h[1] = (_Float16)v0.y; h[2] = (_Float16)v0.z; h[3] = (_Float16)v0.w;
    h[4] = (_Float16)v1.x; h[5] = (_Float16)v1.y; h[6] = (_Float16)v1.z; h[7] = (_Float16)v1.w;
    *(half8_t*)(Ah + 8 * (size_t)i) = h;
  } else if (i < ACNT8 + WCNT8) {
    const int j = i - ACNT8;
    const int4 q0 = ((const int4*)q)[2 * (size_t)j];
    const int4 q1 = ((const int4*)q)[2 * (size_t)j + 1];
    uint2 p;
    p.x = (q0.x & 0xFFu) | ((q0.y & 0xFFu) << 8) | ((q0.z & 0xFFu) << 16) | ((unsigned)(q0.w & 0xFFu) << 24);
    p.y = (q1.x & 0xFFu) | ((q1.y & 0xFFu) << 8) | ((q1.z & 0xFFu) << 16) | ((unsigned)(q1.w & 0xFFu) << 24);
    ((uint2*)Wq)[j] = p;
  } else {
    const int e = i - ACNT8 - WCNT8;   // e = n*32 + g  (coalesced reads)
    const int n = e >> 5;
    const int g = e & 31;
    const float s = scales[e];
    const float z = zeros[e];
    const float c = -z * s;
    union { _Float16 h; unsigned short u; } sh, ch;
    sh.h = (_Float16)s; ch.h = (_Float16)c;
    SZT[(size_t)g * NN + n] = (unsigned)sh.u | ((unsigned)ch.u << 16);
  }
}

// ---------------------------------------------------------------------------
// R11 main GEMM = R10 with the stageB source-address bug fixed.
//
// R10 failed (absmax 22.7) because stageB's global source had a spurious
// "- bcc*16": global_load_lds's source is the per-lane pointer ITSELF (no
// implicit lane term), so the subtraction made all 4 lanes of a row fetch
// overlapping 16B chunks -> garbage B tiles. Correct source: row r, logical
// 16B chunk g16 = (l&3) ^ ((r>>1)&3). (stageA always did this correctly.)
//
// Experiment (unchanged from R10's intent, m145 precedent): stage B as raw
// uint8 (16 KB/tile instead of 32), dequant in-register to f16:
//   - staging 48 -> 32 KB/tile; HBM fetch for W: 32 -> 16 MB
//   - B LDS reads b128 -> b64
//   - per-(n,g) (s, -z*s) f16x2 constants from a 32 KB LDS table (sSZ),
//     staged once in the prologue, refreshed into 4 regs every 2 tiles.
//
// Ledger (per wave): 4 staging calls/tile (B 2 in phase 0, A 2 in phase 1).
// Boundary wait vmcnt(4) = tile t+1 landed, t+2's 4 in flight. Prologue:
// SZ 4 + t0 4 + t1 4 issued, wait vmcnt(4) = SZ+t0 landed.
//
// Bq LDS swizzle (rule 21, same involution both sides): physical 8B-chunk p
// of row r holds logical chunk p ^ (r&6). Staging lane l covers row
// base+(l>>2), physical 16B-chunk l&3, global 16B chunk (l&3)^((r>>1)&3)
// (bit0 of the 8B-chunk index is preserved inside the 16B DMA, so this is
// exactly p^(r&6) at 8B granularity). Read: p8 = (ks*4+quad) ^ (row&6),
// where row&6 == (l>>2)&6 holds because c*128 and wave*16 are 0 mod 8.
// A-path staging/swizzle/reads unchanged from R7 (verified, 0 conflicts).
// ---------------------------------------------------------------------------
__global__ __launch_bounds__(512, 2)
void gemm8_kernel(const _Float16* __restrict__ Ah, const unsigned char* __restrict__ Wq,
                  const unsigned* __restrict__ SZT,
                  const float* __restrict__ bias, float* __restrict__ out)
{
  __shared__ __align__(16) _Float16 sA[3][BM * BK];          // 3 x 16 KiB
  __shared__ __align__(16) unsigned char sBq[3][BN * BK];    // 3 x 16 KiB
  __shared__ __align__(16) unsigned sSZ[GG * BN];            // 32 KiB

  const int tid = threadIdx.x;
  const int lane = tid & 63;
  const int wave = tid >> 6;        // 0..7
  const int wr = wave >> 2;         // 0..1  (m-row of wave, 64 tall)
  const int wc = wave & 3;          // 0..3  (n-col of wave, 64 wide)
  const int lr = lane & 15, quad = lane >> 4;

  // XCD-aware swizzle: 256 blocks, 8 XCDs round-robin by bid.
  const int bid = blockIdx.x;
  const int xcd = bid & 7;
  const int slot = bid >> 3;        // 0..31
  const int mt = slot >> 1;         // 0..15
  const int nt = xcd * 2 + (slot & 1);
  const int m0 = mt * BM;
  const int n0 = nt * BN;

  // A staging geometry: lane l -> row +(l>>3), physical 16B chunk l&7,
  // global chunk (l&7)^(l>>3). Reads use j ^ (lr&7).
  const int srow = lane >> 3, scc = lane & 7, gchA = scc ^ srow;
  // Bq staging geometry: lane l -> row +(l>>2), physical 16B-chunk l&3,
  // global 16B chunk (l&3) ^ ((row>>1)&3).
  const int brow = lane >> 2, bcc = lane & 3;

  f32x4 acc[4][4];
#pragma unroll
  for (int i = 0; i < 4; ++i)
#pragma unroll
    for (int j = 0; j < 4; ++j) acc[i][j] = (f32x4){0.f, 0.f, 0.f, 0.f};

  // A: 2 calls/tile (i in {0,1}), rows i*64 + wave*8 + srow.
  auto stageA = [&](int t, int buf, int i) {
    load_lds16(Ah + (size_t)(m0 + i * 64 + (wave << 3) + srow) * KK + t * BK + (gchA << 3),
               (void*)&sA[buf][(i * 64 + (wave << 3)) * BK]);
  };
  // Bq: 2 calls/tile (c in {0,1}), rows c*128 + wave*16 + brow.
  // FIX vs R10: source is row r, chunk g16 -- no "- bcc*16" term.
  auto stageB = [&](int t, int buf, int c) {
    const int r = c * 128 + (wave << 4) + brow;
    const int g16 = bcc ^ ((r >> 1) & 3);
    load_lds16(Wq + (size_t)(n0 + r) * KK + t * BK + g16 * 16,
               (void*)&sBq[buf][(c * 128 + (wave << 4)) * BK]);
  };
  // SZ: 4 calls, wave w stages g-rows {w, 8+w, 16+w, 24+w} (1 KB each).
  auto stageSZ = [&](int c) {
    const int g = c * 8 + wave;
    load_lds16(SZT + (size_t)g * NN + n0 + lane * 4, (void*)&sSZ[g * BN]);
  };

  // Prologue: SZ + tiles 0,1. Per-wave issue: 4 + 4 + 4 = 12; wait vmcnt(4)
  // -> SZ and tile 0 landed, tile 1's 4 in flight.
  stageSZ(0); stageSZ(1); stageSZ(2); stageSZ(3);
  stageB(0, 0, 0); stageB(0, 0, 1); stageA(0, 0, 0); stageA(0, 0, 1);
  stageB(1, 1, 0); stageB(1, 1, 1); stageA(1, 1, 0); stageA(1, 1, 1);
  asm volatile("s_waitcnt vmcnt(4)" ::: "memory");
  __builtin_amdgcn_s_barrier();

  unsigned szv[4];
  int cur = 0, nb = 2;
  for (int t = 0; t < NTILES; ++t) {
    const _Float16* pA = sA[cur];
    const unsigned char* pB = sBq[cur];
    const bool st = (t < NTILES - 2);   // uniform

    if ((t & 1) == 0) {                 // group changes every 2 tiles
      const int g = t >> 1;
#pragma unroll
      for (int ni = 0; ni < 4; ++ni)
        szv[ni] = sSZ[g * BN + wc * 64 + ni * 16 + lr];
    }

    half8_t a0[2][2], a1[2][2], b[4][2];

    // ---- phase 0: A-frags mi 0..1, all B-frags (b64 + dequant) ----
#pragma unroll
    for (int x = 0; x < 2; ++x) {
      const _Float16* ba = &pA[(wr * 64 + x * 16 + lr) * BK];
#pragma unroll
      for (int ks = 0; ks < 2; ++ks)
        a0[x][ks] = *(const half8_t*)&ba[((ks * 4 + quad) ^ (lr & 7)) * 8];
    }
#pragma unroll
    for (int ni = 0; ni < 4; ++ni) {
      const int row = wc * 64 + ni * 16 + lr;
      const half2_t sc = h2_from_u32(szv[ni]);
      const half2_t s2 = (half2_t){sc[0], sc[0]};
      const half2_t c2 = (half2_t){sc[1], sc[1]};
#pragma unroll
      for (int ks = 0; ks < 2; ++ks) {
        const int p8 = (ks * 4 + quad) ^ (row & 6);
        const uint2 d = *(const uint2*)&pB[row * BK + p8 * 8];
        b[ni][ks] = dq8(d.x, d.y, s2, c2);
      }
    }
    if (st) { stageB(t + 2, nb, 0); stageB(t + 2, nb, 1); }
    __builtin_amdgcn_sched_barrier(0);
    __builtin_amdgcn_s_barrier();
    __builtin_amdgcn_s_setprio(1);
#pragma unroll
    for (int x = 0; x < 2; ++x)
#pragma unroll
      for (int ni = 0; ni < 4; ++ni) {
        acc[x][ni] = __builtin_amdgcn_mfma_f32_16x16x32_f16(a0[x][0], b[ni][0], acc[x][ni], 0, 0, 0);
        acc[x][ni] = __builtin_amdgcn_mfma_f32_16x16x32_f16(a0[x][1], b[ni][1], acc[x][ni], 0, 0, 0);
      }
    __builtin_amdgcn_s_setprio(0);
    __builtin_amdgcn_s_barrier();

    // ---- phase 1: A-frags mi 2..3 (b[] reused from regs) ----
#pragma unroll
    for (int x = 0; x < 2; ++x) {
      const _Float16* ba = &pA[(wr * 64 + (x + 2) * 16 + lr) * BK];
#pragma unroll
      for (int ks = 0; ks < 2; ++ks)
        a1[x][ks] = *(const half8_t*)&ba[((ks * 4 + quad) ^ (lr & 7)) * 8];
    }
    if (st) { stageA(t + 2, nb, 0); stageA(t + 2, nb, 1); }
    __builtin_amdgcn_sched_barrier(0);
    __builtin_amdgcn_s_barrier();
    __builtin_amdgcn_s_setprio(1);
#pragma unroll
    for (int x = 0; x < 2; ++x)
#pragma unroll
      for (int ni = 0; ni < 4; ++ni) {
        acc[x + 2][ni] = __builtin_amdgcn_mfma_f32_16x16x32_f16(a1[x][0], b[ni][0], acc[x + 2][ni], 0, 0, 0);
        acc[x + 2][ni] = __builtin_amdgcn_mfma_f32_16x16x32_f16(a1[x][1], b[ni][1], acc[x + 2][ni], 0, 0, 0);
      }
    __builtin_amdgcn_s_setprio(0);
    // Boundary: t+1's 4 loads landed, t+2's 4 stay in flight.
    if (t < NTILES - 2) asm volatile("s_waitcnt vmcnt(4)" ::: "memory");
    else                asm volatile("s_waitcnt vmcnt(0)" ::: "memory");
    __builtin_amdgcn_s_barrier();
    cur = (cur == 2) ? 0 : cur + 1;
    nb  = (nb  == 2) ? 0 : nb + 1;
  }

  // Epilogue. C/D layout (verified, dtype-independent): col = lane&15,
  // row = quad*4 + reg.
#pragma unroll
  for (int ni = 0; ni < 4; ++ni) {
    const int n = n0 + wc * 64 + ni * 16 + lr;
    const float bv = bias[n];
#pragma unroll
    for (int mi = 0; mi < 4; ++mi) {
      const int mbase = m0 + wr * 64 + mi * 16 + quad * 4;
#pragma unroll
      for (int r = 0; r < 4; ++r)
        out[(size_t)(mbase + r) * NN + n] = acc[mi][ni][r] + bv;
    }
  }
}

// Fallback (ws too small): previous verified 128x128 fused-dequant kernel.
__global__ __launch_bounds__(256, 2)
void gemm_fused_kernel(const float* __restrict__ Af, const int* __restrict__ qw,
                       const float* __restrict__ scales, const float* __restrict__ zeros,
                       const float* __restrict__ bias, float* __restrict__ out)
{
  __shared__ __align__(16) _Float16 sA[128 * 64];
  __shared__ __align__(16) _Float16 sB[128 * 64];

  const int tid = threadIdx.x;
  const int lane = tid & 63;
  const int wave = tid >> 6;
  const int wr = wave >> 1, wc = wave & 1;

  const int bid = blockIdx.x;
  const int xcd = bid & 7;
  const int slot = bid >> 3;
  const int mt = slot >> 2;
  const int nt = xcd * 4 + (slot & 3);
  const int m0 = mt * 128;
  const int n0 = nt * 128;

  const int lr = lane & 15, quad = lane >> 4;

  f32x4 acc[4][4];
#pragma unroll
  for (int i = 0; i < 4; ++i)
#pragma unroll
    for (int j = 0; j < 4; ++j) acc[i][j] = (f32x4){0.f, 0.f, 0.f, 0.f};

  const int frow = tid >> 4;
  const int fc4 = tid & 15;

  for (int kt = 0; kt < KK / 64; ++kt) {
    const int k0 = kt * 64;
    const int g = k0 >> 7;
#pragma unroll
    for (int p = 0; p < 8; ++p) {
      const int row = p * 16 + frow;
      const int pc = (fc4 >> 1) ^ (row & 7);
      const int dst = row * 64 + pc * 8 + (fc4 & 1) * 4;
      const float4 avf = *(const float4*)&Af[(size_t)(m0 + row) * KK + k0 + fc4 * 4];
      half4_t ah;
      ah[0] = (_Float16)avf.x; ah[1] = (_Float16)avf.y;
      ah[2] = (_Float16)avf.z; ah[3] = (_Float16)avf.w;
      *(half4_t*)&sA[dst] = ah;
      const int n = n0 + row;
      const float sc = scales[(n << 5) + g];
      const float zp = zeros[(n << 5) + g];
      const float nzs = -zp * sc;
      const int4 qv = *(const int4*)&qw[(size_t)n * KK + k0 + fc4 * 4];
      half4_t bh;
      bh[0] = (_Float16)fmaf((float)qv.x, sc, nzs);
      bh[1] = (_Float16)fmaf((float)qv.y, sc, nzs);
      bh[2] = (_Float16)fmaf((float)qv.z, sc, nzs);
      bh[3] = (_Float16)fmaf((float)qv.w, sc, nzs);
      *(half4_t*)&sB[dst] = bh;
    }
    __syncthreads();
#pragma unroll
    for (int ks = 0; ks < 2; ++ks) {
      half8_t a[4], b[4];
#pragma unroll
      for (int t = 0; t < 4; ++t) {
        const int rA = wr * 64 + t * 16 + lr;
        const int j = ks * 4 + quad;
        a[t] = *(const half8_t*)&sA[rA * 64 + ((j ^ (lr & 7)) * 8)];
        const int rB = wc * 64 + t * 16 + lr;
        b[t] = *(const half8_t*)&sB[rB * 64 + ((j ^ (lr & 7)) * 8)];
      }
#pragma unroll
      for (int mi = 0; mi < 4; ++mi)
#pragma unroll
        for (int ni = 0; ni < 4; ++ni)
          acc[mi][ni] = __builtin_amdgcn_mfma_f32_16x16x32_f16(a[mi], b[ni], acc[mi][ni], 0, 0, 0);
    }
    __syncthreads();
  }

#pragma unroll
  for (int ni = 0; ni < 4; ++ni) {
    const int n = n0 + wc * 64 + ni * 16 + lr;
    const float bv = bias[n];
#pragma unroll
    for (int mi = 0; mi < 4; ++mi) {
      const int mbase = m0 + wr * 64 + mi * 16 + quad * 4;
#pragma unroll
      for (int r = 0; r < 4; ++r)
        out[(size_t)(mbase + r) * NN + n] = acc[mi][ni][r] + bv;
    }
  }
}

extern "C" void kernel_launch(void* const* d_in, const int* in_sizes, int n_in,
                              void* d_out, int out_size, void* d_ws, size_t ws_size,
                              hipStream_t stream) {
  (void)in_sizes; (void)n_in; (void)out_size;
  const float* A      = (const float*)d_in[0];
  const int*   qw     = (const int*)d_in[1];
  const float* scales = (const float*)d_in[2];
  const float* zeros  = (const float*)d_in[3];
  const float* bias   = (const float*)d_in[4];
  float* out = (float*)d_out;

  const size_t needA  = (size_t)MM * KK * sizeof(_Float16);   // 16 MB
  const size_t needWq = (size_t)NN * KK;                      // 16 MB
  const size_t needSZ = (size_t)NN * GG * sizeof(unsigned);   // 512 KB

  if (ws_size >= needA + needWq + needSZ) {
    _Float16*      Ah  = (_Float16*)d_ws;
    unsigned char* Wq  = (unsigned char*)d_ws + needA;
    unsigned*      SZT = (unsigned*)((char*)d_ws + needA + needWq);
    prep_kernel<<<(ACNT8 + WCNT8 + SZCNT) / 256, 256, 0, stream>>>(A, qw, scales, zeros, Ah, Wq, SZT);
    gemm8_kernel<<<dim3(MM / BM * NN / BN), dim3(512), 0, stream>>>(Ah, Wq, SZT, bias, out);
  } else {
    gemm_fused_kernel<<<dim3(512), dim3(256), 0, stream>>>(A, qw, scales, zeros, bias, out);
  }
}

// Round 6
// 230.978 us; speedup vs baseline: 1.0352x; 1.0352x over previous
//
#include <hip/hip_runtime.h>
#include <cstdint>
#include <cstddef>

// Shapes fixed by the reference harness.
#define MM 2048
#define KK 4096
#define NN 4096
#define GG 32   // K / 128 groups
#define BM 128
#define BN 256
#define BK 32
#define NTILES (KK / BK)   // 128 k-tiles

typedef _Float16 half8_t __attribute__((ext_vector_type(8)));
typedef _Float16 half4_t __attribute__((ext_vector_type(4)));
typedef float f32x4 __attribute__((ext_vector_type(4)));

__device__ __forceinline__ void load_lds16(const void* gptr, void* lptr) {
  // 16B-per-lane direct global->LDS (emits global_load_lds_dwordx4).
  // LDS dest = wave-uniform base + lane*16 (implicit); the GLOBAL source is
  // exactly the per-lane pointer passed (no implicit lane term).
  __builtin_amdgcn_global_load_lds(
      (const __attribute__((address_space(1))) unsigned int*)gptr,
      (__attribute__((address_space(3))) unsigned int*)lptr, 16, 0, 0);
}

// Merged prep (R7 version, verified): first MM*KK/8 threads convert A
// fp32->fp16; the rest dequant qweight -> fp16 via w = fma(q, s, -z*s).
// 8 elements/thread: 2x16B loads, 1x16B store. Block-uniform branch.
#define ACNT8 (MM * KK / 8)   // 1M half8-threads for A
__global__ void prep_kernel(const float* __restrict__ A, const int* __restrict__ q,
                            const float* __restrict__ scales, const float* __restrict__ zeros,
                            _Float16* __restrict__ Ah, _Float16* __restrict__ Wh) {
  const int i = blockIdx.x * blockDim.x + threadIdx.x;
  if (i < ACNT8) {
    const float4 v0 = ((const float4*)A)[2 * (size_t)i];
    const float4 v1 = ((const float4*)A)[2 * (size_t)i + 1];
    half8_t h;
    h[0] = (_Float16)v0.x; h[1] = (_Float16)v0.y; h[2] = (_Float16)v0.z; h[3] = (_Float16)v0.w;
    h[4] = (_Float16)v1.x; h[5] = (_Float16)v1.y; h[6] = (_Float16)v1.z; h[7] = (_Float16)v1.w;
    *(half8_t*)(Ah + 8 * (size_t)i) = h;
  } else {
    const int j = i - ACNT8;
    const int e = j << 3;         // element index
    const int n = e >> 12;        // / KK
    const int k = e & (KK - 1);
    const int g = k >> 7;         // / 128 (8 consecutive k share a group)
    const float sc = scales[(n << 5) + g];
    const float zp = zeros[(n << 5) + g];
    const float nzs = -zp * sc;
    const int4 q0 = ((const int4*)q)[2 * (size_t)j];
    const int4 q1 = ((const int4*)q)[2 * (size_t)j + 1];
    half8_t h;
    h[0] = (_Float16)fmaf((float)q0.x, sc, nzs);
    h[1] = (_Float16)fmaf((float)q0.y, sc, nzs);
    h[2] = (_Float16)fmaf((float)q0.z, sc, nzs);
    h[3] = (_Float16)fmaf((float)q0.w, sc, nzs);
    h[4] = (_Float16)fmaf((float)q1.x, sc, nzs);
    h[5] = (_Float16)fmaf((float)q1.y, sc, nzs);
    h[6] = (_Float16)fmaf((float)q1.z, sc, nzs);
    h[7] = (_Float16)fmaf((float)q1.w, sc, nzs);
    *(half8_t*)(Wh + (size_t)e) = h;
  }
}

// ---------------------------------------------------------------------------
// R12 main GEMM: LDS-port-volume geometry. Evidence: R6/R7/R8 (three sync
// structures) all ~80us @ ~35% MfmaUtil; what they share is per-block LDS
// traffic: 8 waves x (64+64) x 4096 x 2B = 8.4 MB ds_read + 3 MB DMA write
// -> ~41 + ~10 us of LDS-port time at the measured 85 B/cyc b128 rate, vs
// 27.5 us MFMA. The LDS port is the longest pipe; max() + barrier residue
// = the observed 80. R9 (ratio 0.375 via split-K) spent its gain on a
// conflicted reduction epilogue. R11 (int8 B + in-loop dequant) showed
// in-loop VALU dequant is 3x MFMA time -> dead.
//
// This round: 4 waves of 64x128 on the same 128x256 block (read volume
// 4 x 192 x 4096 x 2B = 6.3 MB, -25%) with NO epilogue tax. BK=32 so LDS
// rows are 64 B -- naturally conflict-free for both the linear DMA dest and
// the b128 frag reads (row stride = half the 128B bank width; the 16-row x
// 4-chunk access covers all 32 banks each cycle). No swizzle anywhere.
// 3 buffers x 24 KB = 72 KB -> 2 blocks/CU (8 waves/CU, occupancy kept).
// One barrier + one counted vmcnt per K-tile (128 tiles).
//
// Ledger (per wave): 6 staging calls/tile (A 2, B 4). Boundary: vmcnt(6)
// = tile t+1's loads landed, t+2's 6 in flight (vmcnt(0) only for the last
// two tiles). Prologue: 12 issued, vmcnt(6) = tile 0 landed.
// Buffer rotation runtime-indexed (R7-style; measured better than R8's
// static rotation). Staging overwrite safety: buf[(t+2)%3] last read at
// tile t-1, whose reads retire before its end-of-tile barrier.
// ---------------------------------------------------------------------------
__global__ __launch_bounds__(256, 2)
void gemm12_kernel(const _Float16* __restrict__ Ah, const _Float16* __restrict__ Wh,
                   const float* __restrict__ bias, float* __restrict__ out)
{
  __shared__ __align__(16) _Float16 sA[3][BM * BK];   // 3 x 8 KiB
  __shared__ __align__(16) _Float16 sB[3][BN * BK];   // 3 x 16 KiB

  const int tid = threadIdx.x;
  const int lane = tid & 63;
  const int wave = tid >> 6;        // 0..3
  const int wr = wave >> 1;         // 0..1  (m-row of wave, 64 tall)
  const int wc = wave & 1;          // 0..1  (n-col of wave, 128 wide)
  const int lr = lane & 15, quad = lane >> 4;

  // XCD-aware swizzle: 256 blocks, 8 XCDs round-robin by bid.
  const int bid = blockIdx.x;
  const int xcd = bid & 7;
  const int slot = bid >> 3;        // 0..31
  const int mt = slot >> 1;         // 0..15
  const int nt = xcd * 2 + (slot & 1);
  const int m0 = mt * BM;
  const int n0 = nt * BN;

  // Staging geometry: per call a wave covers 16 rows x 32 halves (1 KiB
  // linear LDS). Lane l -> row +(l>>2), 16B k-chunk (l&3). Plain row-major,
  // no swizzle (64B rows are conflict-free, see header).
  const int srow = lane >> 2, sch = lane & 3;

  f32x4 acc[4][8];
#pragma unroll
  for (int i = 0; i < 4; ++i)
#pragma unroll
    for (int j = 0; j < 8; ++j) acc[i][j] = (f32x4){0.f, 0.f, 0.f, 0.f};

  // A: 2 calls/tile (i in {0,1}), 16-row slabs (wave*2+i)*16.
  auto stageA = [&](int t, int buf, int i) {
    const int r16 = (wave * 2 + i) * 16;
    load_lds16(Ah + (size_t)(m0 + r16 + srow) * KK + t * BK + sch * 8,
               (void*)&sA[buf][r16 * BK]);
  };
  // B: 4 calls/tile (c in {0..3}), 16-row slabs (wave*4+c)*16.
  auto stageB = [&](int t, int buf, int c) {
    const int r16 = (wave * 4 + c) * 16;
    load_lds16(Wh + (size_t)(n0 + r16 + srow) * KK + t * BK + sch * 8,
               (void*)&sB[buf][r16 * BK]);
  };

  // Prologue: stage tiles 0 and 1 (6 calls each per wave).
  stageB(0, 0, 0); stageB(0, 0, 1); stageB(0, 0, 2); stageB(0, 0, 3);
  stageA(0, 0, 0); stageA(0, 0, 1);
  stageB(1, 1, 0); stageB(1, 1, 1); stageB(1, 1, 2); stageB(1, 1, 3);
  stageA(1, 1, 0); stageA(1, 1, 1);
  asm volatile("s_waitcnt vmcnt(6)" ::: "memory");   // tile 0 landed, tile 1 in flight
  __builtin_amdgcn_s_barrier();

  int cur = 0, nb = 2;
  for (int t = 0; t < NTILES; ++t) {
    const _Float16* pA = sA[cur];
    const _Float16* pB = sB[cur];
    const bool st = (t < NTILES - 2);   // uniform

    // Frag reads: a[4] + b[8] = 12 ds_read_b128 for 32 MFMA (ratio 0.375).
    half8_t a[4], b[8];
#pragma unroll
    for (int mi = 0; mi < 4; ++mi)
      a[mi] = *(const half8_t*)&pA[(wr * 64 + mi * 16 + lr) * BK + quad * 8];
#pragma unroll
    for (int ni = 0; ni < 8; ++ni)
      b[ni] = *(const half8_t*)&pB[(wc * 128 + ni * 16 + lr) * BK + quad * 8];

    if (st) {
      stageB(t + 2, nb, 0); stageB(t + 2, nb, 1); stageB(t + 2, nb, 2); stageB(t + 2, nb, 3);
      stageA(t + 2, nb, 0); stageA(t + 2, nb, 1);
    }
    __builtin_amdgcn_sched_barrier(0);

    __builtin_amdgcn_s_setprio(1);
#pragma unroll
    for (int mi = 0; mi < 4; ++mi)
#pragma unroll
      for (int ni = 0; ni < 8; ++ni)
        acc[mi][ni] = __builtin_amdgcn_mfma_f32_16x16x32_f16(a[mi], b[ni], acc[mi][ni], 0, 0, 0);
    __builtin_amdgcn_s_setprio(0);

    // Boundary: t+1's 6 loads landed, t+2's 6 stay in flight.
    if (t < NTILES - 2) asm volatile("s_waitcnt vmcnt(6)" ::: "memory");
    else                asm volatile("s_waitcnt vmcnt(0)" ::: "memory");
    __builtin_amdgcn_s_barrier();
    cur = (cur == 2) ? 0 : cur + 1;
    nb  = (nb  == 2) ? 0 : nb + 1;
  }

  // Epilogue. C/D layout (verified, dtype-independent): col = lane&15,
  // row = quad*4 + reg.
#pragma unroll
  for (int ni = 0; ni < 8; ++ni) {
    const int n = n0 + wc * 128 + ni * 16 + lr;
    const float bv = bias[n];
#pragma unroll
    for (int mi = 0; mi < 4; ++mi) {
      const int mbase = m0 + wr * 64 + mi * 16 + quad * 4;
#pragma unroll
      for (int r = 0; r < 4; ++r)
        out[(size_t)(mbase + r) * NN + n] = acc[mi][ni][r] + bv;
    }
  }
}

// Fallback (ws too small): previous verified 128x128 fused-dequant kernel.
__global__ __launch_bounds__(256, 2)
void gemm_fused_kernel(const float* __restrict__ Af, const int* __restrict__ qw,
                       const float* __restrict__ scales, const float* __restrict__ zeros,
                       const float* __restrict__ bias, float* __restrict__ out)
{
  __shared__ __align__(16) _Float16 sA[128 * 64];
  __shared__ __align__(16) _Float16 sB[128 * 64];

  const int tid = threadIdx.x;
  const int lane = tid & 63;
  const int wave = tid >> 6;
  const int wr = wave >> 1, wc = wave & 1;

  const int bid = blockIdx.x;
  const int xcd = bid & 7;
  const int slot = bid >> 3;
  const int mt = slot >> 2;
  const int nt = xcd * 4 + (slot & 3);
  const int m0 = mt * 128;
  const int n0 = nt * 128;

  const int lr = lane & 15, quad = lane >> 4;

  f32x4 acc[4][4];
#pragma unroll
  for (int i = 0; i < 4; ++i)
#pragma unroll
    for (int j = 0; j < 4; ++j) acc[i][j] = (f32x4){0.f, 0.f, 0.f, 0.f};

  const int frow = tid >> 4;
  const int fc4 = tid & 15;

  for (int kt = 0; kt < KK / 64; ++kt) {
    const int k0 = kt * 64;
    const int g = k0 >> 7;
#pragma unroll
    for (int p = 0; p < 8; ++p) {
      const int row = p * 16 + frow;
      const int pc = (fc4 >> 1) ^ (row & 7);
      const int dst = row * 64 + pc * 8 + (fc4 & 1) * 4;
      const float4 avf = *(const float4*)&Af[(size_t)(m0 + row) * KK + k0 + fc4 * 4];
      half4_t ah;
      ah[0] = (_Float16)avf.x; ah[1] = (_Float16)avf.y;
      ah[2] = (_Float16)avf.z; ah[3] = (_Float16)avf.w;
      *(half4_t*)&sA[dst] = ah;
      const int n = n0 + row;
      const float sc = scales[(n << 5) + g];
      const float zp = zeros[(n << 5) + g];
      const float nzs = -zp * sc;
      const int4 qv = *(const int4*)&qw[(size_t)n * KK + k0 + fc4 * 4];
      half4_t bh;
      bh[0] = (_Float16)fmaf((float)qv.x, sc, nzs);
      bh[1] = (_Float16)fmaf((float)qv.y, sc, nzs);
      bh[2] = (_Float16)fmaf((float)qv.z, sc, nzs);
      bh[3] = (_Float16)fmaf((float)qv.w, sc, nzs);
      *(half4_t*)&sB[dst] = bh;
    }
    __syncthreads();
#pragma unroll
    for (int ks = 0; ks < 2; ++ks) {
      half8_t a[4], b[4];
#pragma unroll
      for (int t = 0; t < 4; ++t) {
        const int rA = wr * 64 + t * 16 + lr;
        const int j = ks * 4 + quad;
        a[t] = *(const half8_t*)&sA[rA * 64 + ((j ^ (lr & 7)) * 8)];
        const int rB = wc * 64 + t * 16 + lr;
        b[t] = *(const half8_t*)&sB[rB * 64 + ((j ^ (lr & 7)) * 8)];
      }
#pragma unroll
      for (int mi = 0; mi < 4; ++mi)
#pragma unroll
        for (int ni = 0; ni < 4; ++ni)
          acc[mi][ni] = __builtin_amdgcn_mfma_f32_16x16x32_f16(a[mi], b[ni], acc[mi][ni], 0, 0, 0);
    }
    __syncthreads();
  }

#pragma unroll
  for (int ni = 0; ni < 4; ++ni) {
    const int n = n0 + wc * 64 + ni * 16 + lr;
    const float bv = bias[n];
#pragma unroll
    for (int mi = 0; mi < 4; ++mi) {
      const int mbase = m0 + wr * 64 + mi * 16 + quad * 4;
#pragma unroll
      for (int r = 0; r < 4; ++r)
        out[(size_t)(mbase + r) * NN + n] = acc[mi][ni][r] + bv;
    }
  }
}

extern "C" void kernel_launch(void* const* d_in, const int* in_sizes, int n_in,
                              void* d_out, int out_size, void* d_ws, size_t ws_size,
                              hipStream_t stream) {
  (void)in_sizes; (void)n_in; (void)out_size;
  const float* A      = (const float*)d_in[0];
  const int*   qw     = (const int*)d_in[1];
  const float* scales = (const float*)d_in[2];
  const float* zeros  = (const float*)d_in[3];
  const float* bias   = (const float*)d_in[4];
  float* out = (float*)d_out;

  const size_t needA = (size_t)MM * KK * sizeof(_Float16);  // 16 MB
  const size_t needW = (size_t)NN * KK * sizeof(_Float16);  // 32 MB

  if (ws_size >= needA + needW) {
    _Float16* Ah = (_Float16*)d_ws;
    _Float16* Wh = (_Float16*)((char*)d_ws + needA);
    prep_kernel<<<((MM + NN) * KK / 8) / 256, 256, 0, stream>>>(A, qw, scales, zeros, Ah, Wh);
    gemm12_kernel<<<dim3(MM / BM * NN / BN), dim3(256), 0, stream>>>(Ah, Wh, bias, out);
  } else {
    gemm_fused_kernel<<<dim3(512), dim3(256), 0, stream>>>(A, qw, scales, zeros, bias, out);
  }
}